// Round 1
// 485.066 us; speedup vs baseline: 1.0262x; 1.0262x over previous
//
#include <hip/hip_runtime.h>
#include <hip/hip_bf16.h>
#include <stdint.h>

#define N_NODES 50000
#define N_PAD   50048   // 391 * 128
#define E_EDGES 800000
#define MT      391     // row tiles of 128

// src-bucketed CSR: key = dst*NBK + (src>>SRC_SHIFT). Within each node's
// segment, edges come out sorted by src bucket -> concurrent waves sweep t
// low->high together, shrinking the instantaneous gather working set.
#define NBK       16
#define SRC_SHIFT 12          // 50000 >> 12 = 12 -> buckets 0..12 used
#define NKEY      (N_NODES * NBK)

typedef __bf16 bf16x8 __attribute__((ext_vector_type(8)));
typedef __bf16 bf16x4 __attribute__((ext_vector_type(4)));
typedef float  f32x4  __attribute__((ext_vector_type(4)));

// ---------------- CSR build (bucketed) ----------------
__global__ void count_deg(const int* __restrict__ ei, int* __restrict__ cnt) {
    int e = blockIdx.x * blockDim.x + threadIdx.x;
    if (e < E_EDGES) {
        int src = ei[e];
        int dst = ei[E_EDGES + e];
        atomicAdd(&cnt[dst * NBK + (src >> SRC_SHIFT)], 1);
    }
}

#define SCAN_B 1024
__global__ void scan_block(const int* __restrict__ cnt, int* __restrict__ ptr,
                           int* __restrict__ bsum, int n) {
    __shared__ int buf[SCAN_B];
    int i = blockIdx.x * SCAN_B + threadIdx.x;
    int v = (i < n) ? cnt[i] : 0;
    buf[threadIdx.x] = v;
    __syncthreads();
    #pragma unroll
    for (int off = 1; off < SCAN_B; off <<= 1) {
        int t = (threadIdx.x >= (unsigned)off) ? buf[threadIdx.x - off] : 0;
        __syncthreads();
        buf[threadIdx.x] += t;
        __syncthreads();
    }
    if (i < n) ptr[i] = buf[threadIdx.x] - v;
    if (threadIdx.x == SCAN_B - 1) bsum[blockIdx.x] = buf[SCAN_B - 1];
}

// second-level scan: up to 1024 block sums in one block
__global__ void scan_bsums(const int* __restrict__ bsum, int* __restrict__ boff,
                           int nb, int* __restrict__ total_out) {
    __shared__ int buf[SCAN_B];
    int v = ((int)threadIdx.x < nb) ? bsum[threadIdx.x] : 0;
    buf[threadIdx.x] = v;
    __syncthreads();
    #pragma unroll
    for (int off = 1; off < SCAN_B; off <<= 1) {
        int t = (threadIdx.x >= (unsigned)off) ? buf[threadIdx.x - off] : 0;
        __syncthreads();
        buf[threadIdx.x] += t;
        __syncthreads();
    }
    if ((int)threadIdx.x < nb) boff[threadIdx.x] = buf[threadIdx.x] - v;
    if (threadIdx.x == SCAN_B - 1) *total_out = buf[SCAN_B - 1];
}

__global__ void scan_add(int* __restrict__ ptr, const int* __restrict__ boff, int n) {
    int i = blockIdx.x * SCAN_B + threadIdx.x;
    if (i < n) ptr[i] += boff[blockIdx.x];
}

__global__ void fill_csr(const int* __restrict__ ei, const int* __restrict__ ptr2,
                         int* __restrict__ cursor, int* __restrict__ col) {
    int e = blockIdx.x * blockDim.x + threadIdx.x;
    if (e < E_EDGES) {
        int src = ei[e];
        int dst = ei[E_EDGES + e];
        int key = dst * NBK + (src >> SRC_SHIFT);
        int pos = ptr2[key] + atomicAdd(&cursor[key], 1);
        col[pos] = src;
    }
}

// ---------------- one-shot fp32 -> bf16 conversion (x + all weights) -----------
#define XN      3200000
#define WTOT    983040
__global__ void cvt_all(const float* __restrict__ x,
                        const float* __restrict__ Ws1, const float* __restrict__ Ws2,
                        const float* __restrict__ Ws3, const float* __restrict__ Ws4,
                        const float* __restrict__ Wm1, const float* __restrict__ Wl1,
                        const float* __restrict__ Wm2, const float* __restrict__ Wl2,
                        __bf16* __restrict__ xb, __bf16* __restrict__ wbuf) {
    int i = blockIdx.x * blockDim.x + threadIdx.x;
    if (i < XN) { xb[i] = (__bf16)x[i]; return; }
    int j = i - XN;
    if (j >= WTOT) return;
    const float* s; int o;
    if      (j <  32768) { s = Ws1; o = j; }
    else if (j < 294912) { s = Ws2; o = j -  32768; }
    else if (j < 557056) { s = Ws3; o = j - 294912; }
    else if (j < 819200) { s = Ws4; o = j - 557056; }
    else if (j < 884736) { s = Wm1; o = j - 819200; }
    else if (j < 950272) { s = Wl1; o = j - 884736; }
    else if (j < 966656) { s = Wm2; o = j - 950272; }
    else                 { s = Wl2; o = j - 966656; }
    wbuf[j] = (__bf16)s[o];
}

// ---------------- aggregation 0: 64-wide rows, 8 lanes x 16B per edge ----------
// One wave per node; 8 edge-slots of 8 lanes each -> 8 edges per gather instr
// (1 KB/instr vs 128 B with scalar-bf16 lanes). Reduce slots with 3 shfl_xor.
__global__ __launch_bounds__(256) void agg0_gather(
    const __bf16* __restrict__ xb, const int* __restrict__ ptr2,
    const int* __restrict__ col, __bf16* __restrict__ out) {
    int node = blockIdx.x * 4 + (threadIdx.x >> 6);
    int lane = threadIdx.x & 63;
    int g    = lane >> 3;          // edge slot 0..7
    int f0   = (lane & 7) << 3;    // feature chunk base
    if (node >= N_PAD) return;
    long o = (long)node * 64 + f0;
    if (node >= N_NODES) {
        if (g == 0) {
            bf16x8 z;
            #pragma unroll
            for (int i = 0; i < 8; ++i) z[i] = (__bf16)0.0f;
            *(bf16x8*)&out[o] = z;
        }
        return;
    }
    float a[8];
    #pragma unroll
    for (int i = 0; i < 8; ++i) a[i] = 0.0f;
    if (g == 0) {   // self term, added once (slot 0 only)
        bf16x8 s = *(const bf16x8*)&xb[o];
        #pragma unroll
        for (int i = 0; i < 8; ++i) a[i] = (float)s[i];
    }
    int e0 = ptr2[node * NBK], e1 = ptr2[node * NBK + NBK];
    int e = e0;
    for (; e + 16 <= e1; e += 16) {       // 16 edges per iter, 2 gathers in flight
        int c0 = col[e + g];
        int c1 = col[e + 8 + g];
        bf16x8 v0 = *(const bf16x8*)&xb[(c0 << 6) + f0];
        bf16x8 v1 = *(const bf16x8*)&xb[(c1 << 6) + f0];
        #pragma unroll
        for (int i = 0; i < 8; ++i) a[i] += (float)v0[i] + (float)v1[i];
    }
    int rem = e1 - e;   // 0..15, wave-uniform
    if (rem > 0) {
        int u0 = (g < rem) ? g : 0;        float m0 = (g < rem) ? 1.0f : 0.0f;
        int i1 = g + 8;
        int u1 = (i1 < rem) ? i1 : 0;      float m1 = (i1 < rem) ? 1.0f : 0.0f;
        int c0 = col[e + u0];
        int c1 = col[e + u1];
        bf16x8 v0 = *(const bf16x8*)&xb[(c0 << 6) + f0];
        bf16x8 v1 = *(const bf16x8*)&xb[(c1 << 6) + f0];
        #pragma unroll
        for (int i = 0; i < 8; ++i) a[i] += m0 * (float)v0[i] + m1 * (float)v1[i];
    }
    // reduce over the 8 slots: xor masks 8,16,32 keep feature chunk, fold slots
    #pragma unroll
    for (int i = 0; i < 8; ++i) {
        a[i] += __shfl_xor(a[i], 8, 64);
        a[i] += __shfl_xor(a[i], 16, 64);
        a[i] += __shfl_xor(a[i], 32, 64);
    }
    if (g == 0) {
        bf16x8 r;
        #pragma unroll
        for (int i = 0; i < 8; ++i) r[i] = (__bf16)a[i];
        *(bf16x8*)&out[o] = r;
    }
}

// ---------------- aggregation t: 256-wide rows, half-wave x 16B per edge -------
// Half-wave (32 lanes x bf16x8 = 512 B = one full row) per node -> 2 edges per
// gather instruction, 8 KB in flight per wave at unroll 8. Fused bias+relu.
__global__ __launch_bounds__(256) void aggt_gather(
    const __bf16* __restrict__ t, const int* __restrict__ ptr2,
    const int* __restrict__ col, const float* __restrict__ b_m1,
    const float* __restrict__ b_l1, __bf16* __restrict__ p) {
    int node = blockIdx.x * 8 + (threadIdx.x >> 5);
    if (node >= N_NODES) return;
    int hl = threadIdx.x & 31;
    int f0 = hl << 3;
    float a[8];
    {
        bf16x8 s = *(const bf16x8*)&t[(node << 8) + f0];
        #pragma unroll
        for (int i = 0; i < 8; ++i) a[i] = (float)s[i];
    }
    int e0 = ptr2[node * NBK], e1 = ptr2[node * NBK + NBK];
    int e = e0;
    for (; e + 8 <= e1; e += 8) {
        int c[8];
        #pragma unroll
        for (int u = 0; u < 8; ++u) c[u] = col[e + u];
        bf16x8 v[8];
        #pragma unroll
        for (int u = 0; u < 8; ++u) v[u] = *(const bf16x8*)&t[(c[u] << 8) + f0];
        #pragma unroll
        for (int u = 0; u < 8; ++u)
            #pragma unroll
            for (int i = 0; i < 8; ++i) a[i] += (float)v[u][i];
    }
    int rem = e1 - e;   // 0..7 per half-wave
    if (rem > 0) {
        // branchless guarded tail: keep all loads independent & in flight;
        // masked slots re-read col[e+0]'s row (L1-hot) and multiply by 0.
        #pragma unroll
        for (int u = 0; u < 7; ++u) {
            int   uu = (u < rem) ? u : 0;
            float m  = (u < rem) ? 1.0f : 0.0f;
            int   cc = col[e + uu];
            bf16x8 v = *(const bf16x8*)&t[(cc << 8) + f0];
            #pragma unroll
            for (int i = 0; i < 8; ++i) a[i] += m * (float)v[i];
        }
    }
    const float* bp = (f0 < 128) ? (b_m1 + f0) : (b_l1 + (f0 - 128));
    f32x4 b0 = *(const f32x4*)bp;
    f32x4 b1 = *(const f32x4*)(bp + 4);
    bf16x8 r;
    #pragma unroll
    for (int i = 0; i < 4; ++i) r[i]     = (__bf16)fmaxf(a[i]     + b0[i], 0.0f);
    #pragma unroll
    for (int i = 0; i < 4; ++i) r[4 + i] = (__bf16)fmaxf(a[4 + i] + b1[i], 0.0f);
    *(bf16x8*)&p[(node << 8) + f0] = r;
}

// ---------------- bf16 MFMA GEMM core: C[M,N] = A[M,K]*W[N,K]^T, BK=64 ---------
// Tile 128x128, 4 waves (64x64 each, acc 4x4 = 64 VGPRs). LDS 32 KB (As|Ws).
// LDS layout: row r (64 k-elems, 8 granules of 8): granule kt at slot kt^(r&7).
__device__ __forceinline__ void gl_lds16(const __bf16* g, __bf16* l) {
    __builtin_amdgcn_global_load_lds(
        (const __attribute__((address_space(1))) uint32_t*)g,
        (__attribute__((address_space(3))) uint32_t*)l, 16, 0, 0);
}

// XCD-aware swizzle: linear ids round-robin XCDs (id%8); NCOL y-tiles of one
// x-strip land on the same XCD back-to-back -> A-strip L2-resident.
template <int NCOL>
__device__ __forceinline__ void swizzle_xy(int bid, int& x, int& y) {
    int grp  = bid / (8 * NCOL);
    int rem  = bid - grp * (8 * NCOL);
    int base = grp * 8;
    int width = MT - base; if (width > 8) width = 8;
    x = base + rem % width;
    y = rem / width;
}

template <int ACT, bool BIAS, bool OUT_BF16, bool MCHK>
__device__ __forceinline__ void gemm_core(
    const __bf16* __restrict__ A, int lda, const __bf16* __restrict__ W,
    const float* __restrict__ bias, void* __restrict__ Cout, int ldc,
    int K, long Mstore, long blockRow, int blockCol,
    __bf16* __restrict__ smem) {
    __bf16* As = smem;
    __bf16* Ws = smem + 8192;
    const int tid  = threadIdx.x;
    const int wid  = tid >> 6;
    const int lane = tid & 63;
    const int wm = (wid >> 1) << 6;
    const int wn = (wid & 1) << 6;

    f32x4 acc[4][4];
    #pragma unroll
    for (int i = 0; i < 4; ++i)
        #pragma unroll
        for (int j = 0; j < 4; ++j) acc[i][j] = (f32x4)0.0f;

    // staging: wave w owns chunks 4w..4w+3 (1 KB = 8 rows x 128 B each)
    const int srow = lane >> 3;            // row within 8-row chunk
    const int skg  = (lane & 7) ^ srow;    // true k-granule for swizzled slot
    const __bf16* gA[4]; const __bf16* gW[4];
    __bf16 *lA[4], *lW[4];
    #pragma unroll
    for (int i = 0; i < 4; ++i) {
        int c = wid * 4 + i;
        gA[i] = A + (blockRow + c * 8 + srow) * (long)lda + skg * 8;
        gW[i] = W + ((long)blockCol + c * 8 + srow) * (long)K + skg * 8;
        lA[i] = As + c * 512;
        lW[i] = Ws + c * 512;
    }

    const int rA = lane & 15;
    const int q  = lane >> 4;
    const int r7 = rA & 7;

    for (int k0 = 0; k0 < K; k0 += 64) {
        #pragma unroll
        for (int i = 0; i < 4; ++i) gl_lds16(gA[i] + k0, lA[i]);
        #pragma unroll
        for (int i = 0; i < 4; ++i) gl_lds16(gW[i] + k0, lW[i]);
        __syncthreads();

        #pragma unroll
        for (int s = 0; s < 2; ++s) {
            const int slot = ((s * 4 + q) ^ r7) * 8;
            bf16x8 af[4], bf[4];
            #pragma unroll
            for (int mi = 0; mi < 4; ++mi)
                af[mi] = *(const bf16x8*)&As[(wm + mi * 16 + rA) * 64 + slot];
            #pragma unroll
            for (int ni = 0; ni < 4; ++ni)
                bf[ni] = *(const bf16x8*)&Ws[(wn + ni * 16 + rA) * 64 + slot];
            #pragma unroll
            for (int mi = 0; mi < 4; ++mi)
                #pragma unroll
                for (int ni = 0; ni < 4; ++ni)
                    acc[mi][ni] = __builtin_amdgcn_mfma_f32_16x16x32_bf16(
                        af[mi], bf[ni], acc[mi][ni], 0, 0, 0);
        }
        __syncthreads();
    }

    // epilogue: C/D layout col=lane&15, row=(lane>>4)*4+reg
    const int ccol = lane & 15;
    const int crow = (lane >> 4) << 2;
    if (OUT_BF16 && !MCHK) {
        // fast path: stage C tile (128x128 bf16 = 32 KB) in dead As/Ws LDS,
        // then 8 coalesced 16-B stores per thread (1 KB per wave-store).
        #pragma unroll
        for (int mi = 0; mi < 4; ++mi) {
            #pragma unroll
            for (int ni = 0; ni < 4; ++ni) {
                int gc = wn + ni * 16 + ccol;
                float bv = BIAS ? bias[blockCol + gc] : 0.0f;
                #pragma unroll
                for (int r = 0; r < 4; ++r) {
                    float v = acc[mi][ni][r] + bv;
                    if (ACT == 1) v = (v > 0.0f) ? v : 0.1f * v;
                    else if (ACT == 2) v = fmaxf(v, 0.0f);
                    smem[(wm + mi * 16 + crow + r) * 128 + gc] = (__bf16)v;
                }
            }
        }
        __syncthreads();
        #pragma unroll
        for (int i = 0; i < 8; ++i) {
            int o   = (i * 256 + tid) * 8;       // flat elem offset in 128x128
            int row = o >> 7;
            int co  = o & 127;
            *(bf16x8*)((__bf16*)Cout + (blockRow + row) * (long)ldc + blockCol + co) =
                *(const bf16x8*)&smem[o];
        }
    } else {
        #pragma unroll
        for (int mi = 0; mi < 4; ++mi) {
            #pragma unroll
            for (int ni = 0; ni < 4; ++ni) {
                long gr0 = blockRow + wm + mi * 16 + crow;
                int  gc  = blockCol + wn + ni * 16 + ccol;
                float bv = BIAS ? bias[gc] : 0.0f;
                #pragma unroll
                for (int r = 0; r < 4; ++r) {
                    long gr = gr0 + r;
                    if (!MCHK || gr < Mstore) {
                        float v = acc[mi][ni][r] + bv;
                        if (ACT == 1) v = (v > 0.0f) ? v : 0.1f * v;
                        else if (ACT == 2) v = fmaxf(v, 0.0f);
                        if (OUT_BF16) ((__bf16*)Cout)[gr * ldc + gc] = (__bf16)v;
                        else          ((float*)Cout)[gr * ldc + gc] = v;
                    }
                }
            }
        }
    }
}

template <int NCOL, int ACT, bool BIAS, bool OUT_BF16, bool MCHK>
__global__ __launch_bounds__(256) void gemm_bt(
    const __bf16* __restrict__ A, int lda, const __bf16* __restrict__ W,
    const float* __restrict__ bias, void* __restrict__ Cout, int ldc,
    int K, long Mstore) {
    __shared__ __bf16 smem[128 * 128];   // K-loop: As|Ws (32 KB); epilogue: C tile
    int x, y;
    swizzle_xy<NCOL>(blockIdx.x, x, y);
    gemm_core<ACT, BIAS, OUT_BF16, MCHK>(A, lda, W, bias, Cout, ldc, K, Mstore,
                                         (long)x * 128, y * 128, smem);
}

// both heads in one 1D dispatch; swizzled so both heads of one p-strip share
// an XCD. K=128 (each head uses its half of p), lda=256.
__global__ __launch_bounds__(256) void gemm_heads(
    const __bf16* __restrict__ p, const __bf16* __restrict__ wm2,
    const float* __restrict__ b_m2, float* __restrict__ mu,
    const __bf16* __restrict__ wl2, const float* __restrict__ b_l2,
    float* __restrict__ lv) {
    __shared__ __bf16 smem[128 * 128];
    int x, hd;
    swizzle_xy<2>(blockIdx.x, x, hd);
    if (hd == 0)
        gemm_core<0, true, false, true>(p, 256, wm2, b_m2, mu, 128, 128, N_NODES,
                                        (long)x * 128, 0, smem);
    else
        gemm_core<0, true, false, true>(p + 128, 256, wl2, b_l2, lv, 128, 128, N_NODES,
                                        (long)x * 128, 0, smem);
}

extern "C" void kernel_launch(void* const* d_in, const int* in_sizes, int n_in,
                              void* d_out, int out_size, void* d_ws, size_t ws_size,
                              hipStream_t stream) {
    const float* x    = (const float*)d_in[0];
    const int*   ei   = (const int*)d_in[1];
    const float* W_s1 = (const float*)d_in[2];
    const float* b_s1 = (const float*)d_in[3];
    const float* W_s2 = (const float*)d_in[4];
    const float* b_s2 = (const float*)d_in[5];
    const float* W_s3 = (const float*)d_in[6];
    const float* b_s3 = (const float*)d_in[7];
    const float* W_s4 = (const float*)d_in[8];
    const float* b_s4 = (const float*)d_in[9];
    const float* W_m1 = (const float*)d_in[10];
    const float* b_m1 = (const float*)d_in[11];
    const float* W_m2 = (const float*)d_in[12];
    const float* b_m2 = (const float*)d_in[13];
    const float* W_l1 = (const float*)d_in[14];
    const float* b_l1 = (const float*)d_in[15];
    const float* W_l2 = (const float*)d_in[16];
    const float* b_l2 = (const float*)d_in[17];

    char* ws = (char*)d_ws;
    size_t off = 0;
    auto carve = [&](size_t bytes) -> void* {
        void* p = ws + off;
        off = (off + bytes + 255) & ~(size_t)255;
        return p;
    };
    int* ptr2 = (int*)carve((size_t)(NKEY + 1) * 4);
    int* col  = (int*)carve((size_t)E_EDGES * 4);
    int* bsum = (int*)carve(SCAN_B * 4);
    int* boff = (int*)carve(SCAN_B * 4);
    __bf16* wbuf = (__bf16*)carve((size_t)WTOT * 2);
    __bf16* w1  = wbuf;
    __bf16* w2  = wbuf +  32768;
    __bf16* w3  = wbuf + 294912;
    __bf16* w4  = wbuf + 557056;
    __bf16* wml = wbuf + 819200;   // [W_m1 ; W_l1] rows, 256x512
    __bf16* wm2 = wbuf + 950272;
    __bf16* wl2 = wbuf + 966656;
    __bf16* xb    = (__bf16*)carve((size_t)XN * 2);
    __bf16* agg0b = (__bf16*)carve((size_t)N_PAD * 64 * 2);
    __bf16* B1    = (__bf16*)carve((size_t)N_PAD * 512 * 2);
    __bf16* B2    = (__bf16*)carve((size_t)N_PAD * 512 * 2);

    // bucketed count/cursor arrays (3.2 MB each) alias B1/B2 — those buffers
    // are first written only after the CSR build completes (stream-ordered).
    int* cnt2 = (int*)B1;
    int* cur2 = (int*)B2;

    (void)hipMemsetAsync(cnt2, 0, (size_t)NKEY * 4, stream);
    (void)hipMemsetAsync(cur2, 0, (size_t)NKEY * 4, stream);

    // CSR build over NKEY buckets
    const int NB2 = (NKEY + SCAN_B - 1) / SCAN_B;  // 782
    count_deg<<<E_EDGES / 256, 256, 0, stream>>>(ei, cnt2);
    scan_block<<<NB2, SCAN_B, 0, stream>>>(cnt2, ptr2, bsum, NKEY);
    scan_bsums<<<1, SCAN_B, 0, stream>>>(bsum, boff, NB2, &ptr2[NKEY]);
    scan_add<<<NB2, SCAN_B, 0, stream>>>(ptr2, boff, NKEY);
    fill_csr<<<E_EDGES / 256, 256, 0, stream>>>(ei, ptr2, cur2, col);

    // one-shot conversions
    cvt_all<<<(XN + WTOT + 255) / 256, 256, 0, stream>>>(
        x, W_s1, W_s2, W_s3, W_s4, W_m1, W_l1, W_m2, W_l2, xb, wbuf);

    // first aggregation
    agg0_gather<<<N_PAD / 4, 256, 0, stream>>>(xb, ptr2, col, agg0b);

    // shared MLP: 64->512->512->512->512, lrelu x3, final +b then relu
    gemm_bt<4, 1, true, true, false><<<MT * 4, 256, 0, stream>>>(agg0b, 64, w1, b_s1, B1, 512, 64, N_PAD);
    gemm_bt<4, 1, true, true, false><<<MT * 4, 256, 0, stream>>>(B1, 512, w2, b_s2, B2, 512, 512, N_PAD);
    gemm_bt<4, 1, true, true, false><<<MT * 4, 256, 0, stream>>>(B2, 512, w3, b_s3, B1, 512, 512, N_PAD);
    gemm_bt<4, 2, true, true, false><<<MT * 4, 256, 0, stream>>>(B1, 512, w4, b_s4, B2, 512, 512, N_PAD);

    // project h -> 256 (mu|logvar heads) BEFORE aggregation; bf16 out
    __bf16* t = B1;  // N_PAD x 256 bf16
    gemm_bt<2, 0, false, true, false><<<MT * 2, 256, 0, stream>>>(B2, 512, wml, nullptr, t, 256, 512, N_PAD);

    // second aggregation, fused bias+relu
    __bf16* p = B2;  // N x 256 bf16
    aggt_gather<<<(N_NODES + 7) / 8, 256, 0, stream>>>(t, ptr2, col, b_m1, b_l1, p);

    // heads (one swizzled 1D dispatch)
    float* mu = (float*)d_out;
    float* lv = mu + (size_t)N_NODES * 128;
    gemm_heads<<<MT * 2, 256, 0, stream>>>(p, wm2, b_m2, mu, wl2, b_l2, lv);
}